// Round 1
// baseline (4343.145 us; speedup 1.0000x reference)
//
#include <hip/hip_runtime.h>

#define NN 50000
#define NE 800000
#define D 128
#define UNITS 256

// ---------- degree / normalization ----------
__global__ void deg_kernel(const int* __restrict__ row, const float* __restrict__ w,
                           float* __restrict__ deg, int E) {
    int e = blockIdx.x * blockDim.x + threadIdx.x;
    if (e < E) atomicAdd(&deg[row[e]], w[e]);
}

__global__ void dis_kernel(const float* __restrict__ deg, float* __restrict__ dis, int n) {
    int i = blockIdx.x * blockDim.x + threadIdx.x;
    if (i < n) {
        float d = deg[i];
        dis[i] = d > 0.f ? rsqrtf(d) : 0.f;
    }
}

__global__ void nw_kernel(const int* __restrict__ row, const int* __restrict__ col,
                          const float* __restrict__ w, const float* __restrict__ dis,
                          float* __restrict__ nw, int E) {
    int e = blockIdx.x * blockDim.x + threadIdx.x;
    if (e < E) nw[e] = dis[row[e]] * w[e] * dis[col[e]];
}

// ---------- propagation ----------
__global__ void copy_kernel(const float4* __restrict__ src, float4* __restrict__ dst, int n4) {
    int t = blockIdx.x * blockDim.x + threadIdx.x;
    if (t < n4) dst[t] = src[t];
}

// one edge handled by 32 consecutive threads (4 floats each -> 128 feats)
__global__ void scatter_kernel(const float* __restrict__ hprev, float* __restrict__ hnext,
                               const int* __restrict__ row, const int* __restrict__ col,
                               const float* __restrict__ nw, int E) {
    int tid = blockIdx.x * blockDim.x + threadIdx.x;
    int e = tid >> 5;
    if (e >= E) return;
    int c = (tid & 31) << 2;
    int r = row[e];
    int cl = col[e];
    float w = nw[e];
    const float4 v = *(const float4*)(hprev + (size_t)cl * D + c);
    float* dst = hnext + (size_t)r * D + c;
    atomicAdd(dst + 0, v.x * w);
    atomicAdd(dst + 1, v.y * w);
    atomicAdd(dst + 2, v.z * w);
    atomicAdd(dst + 3, v.w * w);
}

// ---------- epilogue GEMM: C[M,256] += A[M,128] @ B[128,256] ----------
__global__ void initout_kernel(const float* __restrict__ bias, float4* __restrict__ out) {
    int t = blockIdx.x * blockDim.x + threadIdx.x;  // one float4 of out
    int j4 = t & 63;                                // 64 float4 per row
    out[t] = ((const float4*)bias)[j4];
}

__global__ __launch_bounds__(256) void gemm_acc(const float* __restrict__ A,
                                                const float* __restrict__ B,
                                                float* __restrict__ C, int M) {
    __shared__ float As[64][33];
    __shared__ float Bs[32][64];
    int m0 = blockIdx.x * 64;
    int n0 = blockIdx.y * 64;
    int t = threadIdx.x;
    int ty = t >> 4, tx = t & 15;
    float acc[4][4] = {};
    for (int kk = 0; kk < D; kk += 32) {
        // stage A tile: rows m0..m0+63, cols kk..kk+31
        int ar = t >> 3;            // 0..31
        int ac = (t & 7) * 4;       // 0..28
        for (int rr = 0; rr < 64; rr += 32) {
            int m = m0 + ar + rr;
            float4 v = make_float4(0.f, 0.f, 0.f, 0.f);
            if (m < M) v = *(const float4*)(A + (size_t)m * D + kk + ac);
            As[ar + rr][ac + 0] = v.x;
            As[ar + rr][ac + 1] = v.y;
            As[ar + rr][ac + 2] = v.z;
            As[ar + rr][ac + 3] = v.w;
        }
        // stage B tile: rows kk..kk+31, cols n0..n0+63
        int br = t >> 4;            // 0..15
        int bc = (t & 15) * 4;      // 0..60
        for (int rr = 0; rr < 32; rr += 16) {
            float4 v = *(const float4*)(B + (size_t)(kk + br + rr) * UNITS + n0 + bc);
            *(float4*)&Bs[br + rr][bc] = v;
        }
        __syncthreads();
        for (int k = 0; k < 32; ++k) {
            float a[4], b[4];
#pragma unroll
            for (int r = 0; r < 4; ++r) a[r] = As[ty * 4 + r][k];
#pragma unroll
            for (int c = 0; c < 4; ++c) b[c] = Bs[k][tx * 4 + c];
#pragma unroll
            for (int r = 0; r < 4; ++r)
#pragma unroll
                for (int c = 0; c < 4; ++c) acc[r][c] += a[r] * b[c];
        }
        __syncthreads();
    }
#pragma unroll
    for (int r = 0; r < 4; ++r) {
        int m = m0 + ty * 4 + r;
        if (m < M) {
            float* cp = C + (size_t)m * UNITS + n0 + tx * 4;
            float4 old = *(float4*)cp;
            old.x += acc[r][0];
            old.y += acc[r][1];
            old.z += acc[r][2];
            old.w += acc[r][3];
            *(float4*)cp = old;
        }
    }
}

__global__ void relu_kernel(float4* __restrict__ out, int n4) {
    int t = blockIdx.x * blockDim.x + threadIdx.x;
    if (t < n4) {
        float4 v = out[t];
        v.x = fmaxf(v.x, 0.f);
        v.y = fmaxf(v.y, 0.f);
        v.z = fmaxf(v.z, 0.f);
        v.w = fmaxf(v.w, 0.f);
        out[t] = v;
    }
}

extern "C" void kernel_launch(void* const* d_in, const int* in_sizes, int n_in,
                              void* d_out, int out_size, void* d_ws, size_t ws_size,
                              hipStream_t stream) {
    const float* x = (const float*)d_in[0];
    const int* ei = (const int*)d_in[1];
    const float* ew = (const float*)d_in[2];
    const float* W = (const float*)d_in[3];
    const float* bias = (const float*)d_in[4];
    float* out = (float*)d_out;

    const int* row = ei;            // edge_index[0]
    const int* col = ei + NE;       // edge_index[1]

    float* deg = (float*)d_ws;
    float* dis = deg + NN;
    float* nw = dis + NN;
    float* hA = nw + NE;
    float* hB = hA + (size_t)NN * D;

    hipMemsetAsync(deg, 0, NN * sizeof(float), stream);
    deg_kernel<<<(NE + 255) / 256, 256, 0, stream>>>(row, ew, deg, NE);
    dis_kernel<<<(NN + 255) / 256, 256, 0, stream>>>(deg, dis, NN);
    nw_kernel<<<(NE + 255) / 256, 256, 0, stream>>>(row, col, ew, dis, nw, NE);

    // out = bias broadcast
    initout_kernel<<<(NN * (UNITS / 4)) / 256, 256, 0, stream>>>(bias, (float4*)out);

    dim3 ggrid((NN + 63) / 64, UNITS / 64);
    const size_t Wstride = (size_t)D * UNITS;

    // hop 0: out += x @ W0
    gemm_acc<<<ggrid, 256, 0, stream>>>(x, W + 0 * Wstride, out, NN);

    int copy_blocks = (NN * D / 4) / 256;               // exact: 6250
    int scat_blocks = (NE * 32 + 255) / 256;            // 100000

    // hop 1: hA = x + scatter(x); out += hA @ W1
    copy_kernel<<<copy_blocks, 256, 0, stream>>>((const float4*)x, (float4*)hA, NN * D / 4);
    scatter_kernel<<<scat_blocks, 256, 0, stream>>>(x, hA, row, col, nw, NE);
    gemm_acc<<<ggrid, 256, 0, stream>>>(hA, W + 1 * Wstride, out, NN);

    // hop 2: hB = hA + scatter(hA); out += hB @ W2
    copy_kernel<<<copy_blocks, 256, 0, stream>>>((const float4*)hA, (float4*)hB, NN * D / 4);
    scatter_kernel<<<scat_blocks, 256, 0, stream>>>(hA, hB, row, col, nw, NE);
    gemm_acc<<<ggrid, 256, 0, stream>>>(hB, W + 2 * Wstride, out, NN);

    // hop 3: hA = hB + scatter(hB); out += hA @ W3
    copy_kernel<<<copy_blocks, 256, 0, stream>>>((const float4*)hB, (float4*)hA, NN * D / 4);
    scatter_kernel<<<scat_blocks, 256, 0, stream>>>(hB, hA, row, col, nw, NE);
    gemm_acc<<<ggrid, 256, 0, stream>>>(hA, W + 3 * Wstride, out, NN);

    relu_kernel<<<(NN * (UNITS / 4)) / 256, 256, 0, stream>>>((float4*)out, NN * UNITS / 4);
}

// Round 2
// 955.853 us; speedup vs baseline: 4.5437x; 4.5437x over previous
//
#include <hip/hip_runtime.h>

#define NN 50000
#define NE 800000
#define D 128
#define UNITS 256

// ---------- degree + edge counts ----------
__global__ void count_kernel(const int* __restrict__ row, const float* __restrict__ w,
                             float* __restrict__ deg, int* __restrict__ cnt, int E) {
    int e = blockIdx.x * blockDim.x + threadIdx.x;
    if (e < E) {
        int r = row[e];
        atomicAdd(&deg[r], w[e]);
        atomicAdd(&cnt[r], 1);
    }
}

__global__ void dis_kernel(const float* __restrict__ deg, float* __restrict__ dis, int n) {
    int i = blockIdx.x * blockDim.x + threadIdx.x;
    if (i < n) {
        float d = deg[i];
        dis[i] = d > 0.f ? rsqrtf(d) : 0.f;
    }
}

// ---------- exclusive scan of cnt -> row_ptr (single block, chunked Hillis-Steele) ----------
__global__ __launch_bounds__(1024) void scan_kernel(const int* __restrict__ cnt,
                                                    int* __restrict__ row_ptr) {
    __shared__ int buf[1024];
    __shared__ int carry;
    int t = threadIdx.x;
    if (t == 0) carry = 0;
    __syncthreads();
    for (int base = 0; base < NN; base += 1024) {
        int i = base + t;
        int v = (i < NN) ? cnt[i] : 0;
        buf[t] = v;
        __syncthreads();
        for (int off = 1; off < 1024; off <<= 1) {
            int add = (t >= off) ? buf[t - off] : 0;
            __syncthreads();
            buf[t] += add;
            __syncthreads();
        }
        int excl = buf[t] - v;
        if (i < NN) row_ptr[i] = carry + excl;
        __syncthreads();
        if (t == 1023) carry += buf[1023];
        __syncthreads();
    }
    if (t == 0) row_ptr[NN] = carry;
}

// ---------- CSR fill with normalized weights ----------
__global__ void fill_kernel(const int* __restrict__ row, const int* __restrict__ col,
                            const float* __restrict__ w, const float* __restrict__ dis,
                            const int* __restrict__ row_ptr, int* __restrict__ cursor,
                            int* __restrict__ ecol, float* __restrict__ ew, int E) {
    int e = blockIdx.x * blockDim.x + threadIdx.x;
    if (e >= E) return;
    int r = row[e], c = col[e];
    int pos = row_ptr[r] + atomicAdd(&cursor[r], 1);
    ecol[pos] = c;
    ew[pos] = dis[r] * w[e] * dis[c];
}

// ---------- fused propagation: h_next = h_prev (self loop) + sum_e w_e * h_prev[col_e] ----------
// 2 nodes per 256-thread block; 128 threads (= feature lanes) per node.
__global__ __launch_bounds__(256) void gather_kernel(const float* __restrict__ hprev,
                                                     float* __restrict__ hnext,
                                                     const int* __restrict__ row_ptr,
                                                     const int* __restrict__ ecol,
                                                     const float* __restrict__ ew) {
    int node = blockIdx.x * 2 + (threadIdx.x >> 7);
    int f = threadIdx.x & 127;
    if (node >= NN) return;
    int beg = row_ptr[node];
    int end = row_ptr[node + 1];
    float acc = hprev[(size_t)node * D + f];   // self loop, weight 1
    for (int e = beg; e < end; ++e) {
        int c = ecol[e];
        float w = ew[e];
        acc = fmaf(w, hprev[(size_t)c * D + f], acc);
    }
    hnext[(size_t)node * D + f] = acc;
}

// ---------- epilogue GEMM: C[M,256] += A[M,128] @ B[128,256]  (+ optional ReLU) ----------
__global__ void initout_kernel(const float* __restrict__ bias, float4* __restrict__ out) {
    int t = blockIdx.x * blockDim.x + threadIdx.x;
    int j4 = t & 63;
    out[t] = ((const float4*)bias)[j4];
}

__global__ __launch_bounds__(256) void gemm_acc(const float* __restrict__ A,
                                                const float* __restrict__ B,
                                                float* __restrict__ C, int M, int do_relu) {
    __shared__ float As[64][33];
    __shared__ float Bs[32][64];
    int m0 = blockIdx.x * 64;
    int n0 = blockIdx.y * 64;
    int t = threadIdx.x;
    int ty = t >> 4, tx = t & 15;
    float acc[4][4] = {};
    for (int kk = 0; kk < D; kk += 32) {
        int ar = t >> 3;
        int ac = (t & 7) * 4;
        for (int rr = 0; rr < 64; rr += 32) {
            int m = m0 + ar + rr;
            float4 v = make_float4(0.f, 0.f, 0.f, 0.f);
            if (m < M) v = *(const float4*)(A + (size_t)m * D + kk + ac);
            As[ar + rr][ac + 0] = v.x;
            As[ar + rr][ac + 1] = v.y;
            As[ar + rr][ac + 2] = v.z;
            As[ar + rr][ac + 3] = v.w;
        }
        int br = t >> 4;
        int bc = (t & 15) * 4;
        for (int rr = 0; rr < 32; rr += 16) {
            float4 v = *(const float4*)(B + (size_t)(kk + br + rr) * UNITS + n0 + bc);
            *(float4*)&Bs[br + rr][bc] = v;
        }
        __syncthreads();
        for (int k = 0; k < 32; ++k) {
            float a[4], b[4];
#pragma unroll
            for (int r = 0; r < 4; ++r) a[r] = As[ty * 4 + r][k];
#pragma unroll
            for (int c = 0; c < 4; ++c) b[c] = Bs[k][tx * 4 + c];
#pragma unroll
            for (int r = 0; r < 4; ++r)
#pragma unroll
                for (int c = 0; c < 4; ++c) acc[r][c] += a[r] * b[c];
        }
        __syncthreads();
    }
#pragma unroll
    for (int r = 0; r < 4; ++r) {
        int m = m0 + ty * 4 + r;
        if (m < M) {
            float* cp = C + (size_t)m * UNITS + n0 + tx * 4;
            float4 old = *(float4*)cp;
            old.x += acc[r][0];
            old.y += acc[r][1];
            old.z += acc[r][2];
            old.w += acc[r][3];
            if (do_relu) {
                old.x = fmaxf(old.x, 0.f);
                old.y = fmaxf(old.y, 0.f);
                old.z = fmaxf(old.z, 0.f);
                old.w = fmaxf(old.w, 0.f);
            }
            *(float4*)cp = old;
        }
    }
}

extern "C" void kernel_launch(void* const* d_in, const int* in_sizes, int n_in,
                              void* d_out, int out_size, void* d_ws, size_t ws_size,
                              hipStream_t stream) {
    const float* x = (const float*)d_in[0];
    const int* ei = (const int*)d_in[1];
    const float* ew_in = (const float*)d_in[2];
    const float* W = (const float*)d_in[3];
    const float* bias = (const float*)d_in[4];
    float* out = (float*)d_out;

    const int* row = ei;
    const int* col = ei + NE;

    // workspace layout (all 4-byte elements)
    float* deg = (float*)d_ws;                 // NN
    float* dis = deg + NN;                     // NN
    int* cnt = (int*)(dis + NN);               // NN
    int* cursor = cnt + NN;                    // NN
    int* row_ptr = cursor + NN;                // NN+1
    int* ecol = row_ptr + NN + 1;              // NE
    float* ewn = (float*)(ecol + NE);          // NE
    float* hA = ewn + NE;                      // NN*D
    float* hB = hA + (size_t)NN * D;           // NN*D

    hipMemsetAsync(deg, 0, NN * sizeof(float), stream);
    hipMemsetAsync(cnt, 0, NN * sizeof(int), stream);
    hipMemsetAsync(cursor, 0, NN * sizeof(int), stream);

    count_kernel<<<(NE + 255) / 256, 256, 0, stream>>>(row, ew_in, deg, cnt, NE);
    dis_kernel<<<(NN + 255) / 256, 256, 0, stream>>>(deg, dis, NN);
    scan_kernel<<<1, 1024, 0, stream>>>(cnt, row_ptr);
    fill_kernel<<<(NE + 255) / 256, 256, 0, stream>>>(row, col, ew_in, dis, row_ptr, cursor,
                                                      ecol, ewn, NE);

    // out = bias broadcast
    initout_kernel<<<(NN * (UNITS / 4)) / 256, 256, 0, stream>>>(bias, (float4*)out);

    dim3 ggrid((NN + 63) / 64, UNITS / 64);
    const size_t Wstride = (size_t)D * UNITS;
    int gat_blocks = (NN + 1) / 2;

    // hop 0: out += x @ W0
    gemm_acc<<<ggrid, 256, 0, stream>>>(x, W + 0 * Wstride, out, NN, 0);

    // hop 1
    gather_kernel<<<gat_blocks, 256, 0, stream>>>(x, hA, row_ptr, ecol, ewn);
    gemm_acc<<<ggrid, 256, 0, stream>>>(hA, W + 1 * Wstride, out, NN, 0);

    // hop 2
    gather_kernel<<<gat_blocks, 256, 0, stream>>>(hA, hB, row_ptr, ecol, ewn);
    gemm_acc<<<ggrid, 256, 0, stream>>>(hB, W + 2 * Wstride, out, NN, 0);

    // hop 3 (+ fused ReLU in its GEMM)
    gather_kernel<<<gat_blocks, 256, 0, stream>>>(hB, hA, row_ptr, ecol, ewn);
    gemm_acc<<<ggrid, 256, 0, stream>>>(hA, W + 3 * Wstride, out, NN, 1);
}

// Round 3
// 837.862 us; speedup vs baseline: 5.1836x; 1.1408x over previous
//
#include <hip/hip_runtime.h>

#define NN 50000
#define NE 800000
#define D 128
#define UNITS 256

// ---------- degree + edge counts ----------
__global__ void count_kernel(const int* __restrict__ row, const float* __restrict__ w,
                             float* __restrict__ deg, int* __restrict__ cnt, int E) {
    int e = blockIdx.x * blockDim.x + threadIdx.x;
    if (e < E) {
        int r = row[e];
        atomicAdd(&deg[r], w[e]);
        atomicAdd(&cnt[r], 1);
    }
}

__global__ void dis_kernel(const float* __restrict__ deg, float* __restrict__ dis, int n) {
    int i = blockIdx.x * blockDim.x + threadIdx.x;
    if (i < n) {
        float d = deg[i];
        dis[i] = d > 0.f ? rsqrtf(d) : 0.f;
    }
}

// ---------- exclusive scan: thread-serial chunks + one block scan ----------
__global__ __launch_bounds__(1024) void scan_kernel(const int* __restrict__ cnt,
                                                    int* __restrict__ row_ptr) {
    __shared__ int sums[1024];
    int t = threadIdx.x;
    const int CHUNK = (NN + 1023) / 1024;  // 49
    int lo = t * CHUNK;
    int hi = lo + CHUNK < NN ? lo + CHUNK : NN;
    int s = 0;
    for (int i = lo; i < hi; ++i) s += cnt[i];
    sums[t] = s;
    __syncthreads();
    for (int off = 1; off < 1024; off <<= 1) {
        int add = (t >= off) ? sums[t - off] : 0;
        __syncthreads();
        sums[t] += add;
        __syncthreads();
    }
    int run = sums[t] - s;  // exclusive prefix of this chunk
    for (int i = lo; i < hi; ++i) {
        row_ptr[i] = run;
        run += cnt[i];
    }
    if (t == 1023) row_ptr[NN] = run;
}

// ---------- CSR fill with normalized weights ----------
__global__ void fill_kernel(const int* __restrict__ row, const int* __restrict__ col,
                            const float* __restrict__ w, const float* __restrict__ dis,
                            const int* __restrict__ row_ptr, int* __restrict__ cursor,
                            int* __restrict__ ecol, float* __restrict__ ew, int E) {
    int e = blockIdx.x * blockDim.x + threadIdx.x;
    if (e >= E) return;
    int r = row[e], c = col[e];
    int pos = row_ptr[r] + atomicAdd(&cursor[r], 1);
    ecol[pos] = c;
    ew[pos] = dis[r] * w[e] * dis[c];
}

// ---------- fused propagation: h_next = h_prev + sum_e w_e * h_prev[col_e] ----------
// 1 wave (64 threads) per node, float2 per lane; edge loop unrolled x4 for ILP.
__global__ __launch_bounds__(256) void gather_kernel(const float* __restrict__ hprev,
                                                     float* __restrict__ hnext,
                                                     const int* __restrict__ row_ptr,
                                                     const int* __restrict__ ecol,
                                                     const float* __restrict__ ew) {
    int node = blockIdx.x * 4 + (threadIdx.x >> 6);
    int f2 = threadIdx.x & 63;
    if (node >= NN) return;
    const float2* hp = (const float2*)hprev;
    int beg = row_ptr[node];
    int end = row_ptr[node + 1];
    float2 self = hp[(size_t)node * 64 + f2];
    float ax = self.x, ay = self.y;
    int e = beg;
    for (; e + 4 <= end; e += 4) {
        int c0 = ecol[e + 0], c1 = ecol[e + 1], c2 = ecol[e + 2], c3 = ecol[e + 3];
        float w0 = ew[e + 0], w1 = ew[e + 1], w2 = ew[e + 2], w3 = ew[e + 3];
        float2 v0 = hp[(size_t)c0 * 64 + f2];
        float2 v1 = hp[(size_t)c1 * 64 + f2];
        float2 v2 = hp[(size_t)c2 * 64 + f2];
        float2 v3 = hp[(size_t)c3 * 64 + f2];
        ax = fmaf(w0, v0.x, ax); ay = fmaf(w0, v0.y, ay);
        ax = fmaf(w1, v1.x, ax); ay = fmaf(w1, v1.y, ay);
        ax = fmaf(w2, v2.x, ax); ay = fmaf(w2, v2.y, ay);
        ax = fmaf(w3, v3.x, ax); ay = fmaf(w3, v3.y, ay);
    }
    for (; e < end; ++e) {
        int c = ecol[e];
        float w = ew[e];
        float2 v = hp[(size_t)c * 64 + f2];
        ax = fmaf(w, v.x, ax);
        ay = fmaf(w, v.y, ay);
    }
    ((float2*)hnext)[(size_t)node * 64 + f2] = make_float2(ax, ay);
}

// ---------- fused 2-source GEMM: C[M,256] (+)= A0@Wb[0:128] + A1@Wb[128:256] ----------
// flags: bit0 = accumulate into C, bit1 = relu, bit2 = add bias
#define BM 128
#define BN 128
#define BK 32

__global__ __launch_bounds__(256) void gemm_fused(const float* __restrict__ A0,
                                                  const float* __restrict__ A1,
                                                  const float* __restrict__ Wb,
                                                  const float* __restrict__ bias,
                                                  float* __restrict__ C, int M, int flags) {
    __shared__ float As[BK][BM + 1];
    __shared__ float Bs[BK][BN + 4];
    int m0 = blockIdx.x * BM;
    int n0 = blockIdx.y * BN;
    int t = threadIdx.x;
    int tx = t & 15, ty = t >> 4;
    float acc[8][8] = {};
    for (int kk = 0; kk < 256; kk += BK) {
        const float* Asrc = (kk < 128) ? A0 : A1;
        int kloc = kk & 127;
#pragma unroll
        for (int i = 0; i < 4; ++i) {
            int idx = t + i * 256;
            int m = idx >> 3;
            int c = (idx & 7) * 4;
            float4 v = make_float4(0.f, 0.f, 0.f, 0.f);
            if (m0 + m < M) v = *(const float4*)(Asrc + (size_t)(m0 + m) * D + kloc + c);
            As[c + 0][m] = v.x;
            As[c + 1][m] = v.y;
            As[c + 2][m] = v.z;
            As[c + 3][m] = v.w;
        }
#pragma unroll
        for (int i = 0; i < 4; ++i) {
            int idx = t + i * 256;
            int k = idx >> 5;
            int c = (idx & 31) * 4;
            *(float4*)&Bs[k][c] = *(const float4*)(Wb + (size_t)(kk + k) * UNITS + n0 + c);
        }
        __syncthreads();
#pragma unroll
        for (int k = 0; k < BK; ++k) {
            float a[8], b[8];
#pragma unroll
            for (int r = 0; r < 8; ++r) a[r] = As[k][ty * 8 + r];
#pragma unroll
            for (int c = 0; c < 8; ++c) b[c] = Bs[k][tx * 8 + c];
#pragma unroll
            for (int r = 0; r < 8; ++r)
#pragma unroll
                for (int c = 0; c < 8; ++c) acc[r][c] = fmaf(a[r], b[c], acc[r][c]);
        }
        __syncthreads();
    }
#pragma unroll
    for (int r = 0; r < 8; ++r) {
        int m = m0 + ty * 8 + r;
        if (m < M) {
            float* cp = C + (size_t)m * UNITS + n0 + tx * 8;
#pragma unroll
            for (int cc = 0; cc < 8; cc += 4) {
                float4 v = make_float4(acc[r][cc], acc[r][cc + 1], acc[r][cc + 2], acc[r][cc + 3]);
                if (flags & 4) {
                    float4 bv = *(const float4*)(bias + n0 + tx * 8 + cc);
                    v.x += bv.x; v.y += bv.y; v.z += bv.z; v.w += bv.w;
                }
                if (flags & 1) {
                    float4 o = *(float4*)(cp + cc);
                    v.x += o.x; v.y += o.y; v.z += o.z; v.w += o.w;
                }
                if (flags & 2) {
                    v.x = fmaxf(v.x, 0.f); v.y = fmaxf(v.y, 0.f);
                    v.z = fmaxf(v.z, 0.f); v.w = fmaxf(v.w, 0.f);
                }
                *(float4*)(cp + cc) = v;
            }
        }
    }
}

extern "C" void kernel_launch(void* const* d_in, const int* in_sizes, int n_in,
                              void* d_out, int out_size, void* d_ws, size_t ws_size,
                              hipStream_t stream) {
    const float* x = (const float*)d_in[0];
    const int* ei = (const int*)d_in[1];
    const float* ew_in = (const float*)d_in[2];
    const float* W = (const float*)d_in[3];
    const float* bias = (const float*)d_in[4];
    float* out = (float*)d_out;

    const int* row = ei;
    const int* col = ei + NE;

    float* deg = (float*)d_ws;                 // NN
    float* dis = deg + NN;                     // NN
    int* cnt = (int*)(dis + NN);               // NN
    int* cursor = cnt + NN;                    // NN
    int* row_ptr = cursor + NN;                // NN+1
    int* ecol = row_ptr + NN + 1;              // NE
    float* ewn = (float*)(ecol + NE);          // NE
    float* hA = ewn + NE;                      // NN*D (h1, later h3)
    float* hB = hA + (size_t)NN * D;           // NN*D (h2)

    hipMemsetAsync(deg, 0, NN * sizeof(float), stream);
    hipMemsetAsync(cnt, 0, NN * sizeof(int), stream);
    hipMemsetAsync(cursor, 0, NN * sizeof(int), stream);

    count_kernel<<<(NE + 255) / 256, 256, 0, stream>>>(row, ew_in, deg, cnt, NE);
    dis_kernel<<<(NN + 255) / 256, 256, 0, stream>>>(deg, dis, NN);
    scan_kernel<<<1, 1024, 0, stream>>>(cnt, row_ptr);
    fill_kernel<<<(NE + 255) / 256, 256, 0, stream>>>(row, col, ew_in, dis, row_ptr, cursor,
                                                      ecol, ewn, NE);

    int gat_blocks = (NN + 3) / 4;
    dim3 ggrid((NN + BM - 1) / BM, UNITS / BN);

    // h1 = prop(x); h2 = prop(h1)
    gather_kernel<<<gat_blocks, 256, 0, stream>>>(x, hA, row_ptr, ecol, ewn);
    gather_kernel<<<gat_blocks, 256, 0, stream>>>(hA, hB, row_ptr, ecol, ewn);

    // out = bias + x@W0 + h1@W1
    gemm_fused<<<ggrid, 256, 0, stream>>>(x, hA, W, bias, out, NN, 4);

    // h3 = prop(h2)  (reuses hA; GEMM1 already consumed h1 — stream order serializes)
    gather_kernel<<<gat_blocks, 256, 0, stream>>>(hB, hA, row_ptr, ecol, ewn);

    // out = relu(out + h2@W2 + h3@W3)
    gemm_fused<<<ggrid, 256, 0, stream>>>(hB, hA, W + (size_t)256 * UNITS, bias, out, NN, 1 | 2);
}

// Round 4
// 459.826 us; speedup vs baseline: 9.4452x; 1.8221x over previous
//
#include <hip/hip_runtime.h>

#define NN 50000
#define NP 50048   // rows padded to multiple of 128
#define NE 800000
#define D 128
#define UNITS 256
#define KTOT 512

typedef __attribute__((ext_vector_type(8))) short short8;
typedef __attribute__((ext_vector_type(4))) float floatx4;

__device__ inline unsigned short f2b(float f) {          // fp32 -> bf16 RNE
    unsigned u = __float_as_uint(f);
    return (unsigned short)((u + 0x7fff + ((u >> 16) & 1)) >> 16);
}
__device__ inline float2 bx2f(unsigned v) {              // packed bf16x2 -> float2
    float2 r;
    r.x = __uint_as_float(v << 16);
    r.y = __uint_as_float(v & 0xffff0000u);
    return r;
}

// ---------- degree + edge counts ----------
__global__ void count_kernel(const int* __restrict__ row, const float* __restrict__ w,
                             float* __restrict__ deg, int* __restrict__ cnt, int E) {
    int e = blockIdx.x * blockDim.x + threadIdx.x;
    if (e < E) {
        int r = row[e];
        atomicAdd(&deg[r], w[e]);
        atomicAdd(&cnt[r], 1);
    }
}

__global__ void dis_kernel(const float* __restrict__ deg, float* __restrict__ dis, int n) {
    int i = blockIdx.x * blockDim.x + threadIdx.x;
    if (i < n) {
        float d = deg[i];
        dis[i] = d > 0.f ? rsqrtf(d) : 0.f;
    }
}

// ---------- exclusive scan: thread-serial chunks + one block scan ----------
__global__ __launch_bounds__(1024) void scan_kernel(const int* __restrict__ cnt,
                                                    int* __restrict__ row_ptr) {
    __shared__ int sums[1024];
    int t = threadIdx.x;
    const int CHUNK = (NN + 1023) / 1024;
    int lo = t * CHUNK;
    int hi = lo + CHUNK < NN ? lo + CHUNK : NN;
    int s = 0;
    for (int i = lo; i < hi; ++i) s += cnt[i];
    sums[t] = s;
    __syncthreads();
    for (int off = 1; off < 1024; off <<= 1) {
        int add = (t >= off) ? sums[t - off] : 0;
        __syncthreads();
        sums[t] += add;
        __syncthreads();
    }
    int run = sums[t] - s;
    for (int i = lo; i < hi; ++i) {
        row_ptr[i] = run;
        run += cnt[i];
    }
    if (t == 1023) row_ptr[NN] = run;
}

// ---------- CSR fill with normalized weights ----------
__global__ void fill_kernel(const int* __restrict__ row, const int* __restrict__ col,
                            const float* __restrict__ w, const float* __restrict__ dis,
                            const int* __restrict__ row_ptr, int* __restrict__ cursor,
                            int* __restrict__ ecol, float* __restrict__ ew, int E) {
    int e = blockIdx.x * blockDim.x + threadIdx.x;
    if (e >= E) return;
    int r = row[e], c = col[e];
    int pos = row_ptr[r] + atomicAdd(&cursor[r], 1);
    ecol[pos] = c;
    ew[pos] = dis[r] * w[e] * dis[c];
}

// ---------- fp32 -> bf16 convert (x) ----------
__global__ void convx_kernel(const float* __restrict__ x, unsigned* __restrict__ xb) {
    int t = blockIdx.x * blockDim.x + threadIdx.x;  // one per 4 floats (exact grid)
    float4 v = ((const float4*)x)[t];
    uint2 o;
    o.x = (unsigned)f2b(v.x) | ((unsigned)f2b(v.y) << 16);
    o.y = (unsigned)f2b(v.z) | ((unsigned)f2b(v.w) << 16);
    ((uint2*)xb)[t] = o;
}

// ---------- W[512][256] fp32 -> Wt[256][512] bf16 ----------
__global__ __launch_bounds__(256) void transw_kernel(const float* __restrict__ W,
                                                     short* __restrict__ Wt) {
    __shared__ float tile[32][33];
    int kb = blockIdx.x * 32;
    int nb = blockIdx.y * 32;
    int tx = threadIdx.x & 31, ty = threadIdx.x >> 5;  // ty 0..7
    for (int i = 0; i < 32; i += 8)
        tile[ty + i][tx] = W[(size_t)(kb + ty + i) * UNITS + nb + tx];
    __syncthreads();
    for (int i = 0; i < 32; i += 8)
        Wt[(size_t)(nb + ty + i) * KTOT + kb + tx] = (short)f2b(tile[tx][ty + i]);
}

// ---------- propagation (bf16 in/out, fp32 accumulate) ----------
// 1 wave per node, 2 feats (1 packed uint) per lane; x4 ILP unroll.
__global__ __launch_bounds__(256) void gather_kernel(const unsigned* __restrict__ hprev,
                                                     unsigned* __restrict__ hnext,
                                                     const int* __restrict__ row_ptr,
                                                     const int* __restrict__ ecol,
                                                     const float* __restrict__ ew) {
    int node = blockIdx.x * 4 + (threadIdx.x >> 6);
    int f = threadIdx.x & 63;
    if (node >= NN) return;
    int beg = row_ptr[node];
    int end = row_ptr[node + 1];
    float2 a = bx2f(hprev[(size_t)node * 64 + f]);  // self loop, weight 1
    float ax = a.x, ay = a.y;
    int e = beg;
    for (; e + 4 <= end; e += 4) {
        int c0 = ecol[e + 0], c1 = ecol[e + 1], c2 = ecol[e + 2], c3 = ecol[e + 3];
        float w0 = ew[e + 0], w1 = ew[e + 1], w2 = ew[e + 2], w3 = ew[e + 3];
        float2 v0 = bx2f(hprev[(size_t)c0 * 64 + f]);
        float2 v1 = bx2f(hprev[(size_t)c1 * 64 + f]);
        float2 v2 = bx2f(hprev[(size_t)c2 * 64 + f]);
        float2 v3 = bx2f(hprev[(size_t)c3 * 64 + f]);
        ax = fmaf(w0, v0.x, ax); ay = fmaf(w0, v0.y, ay);
        ax = fmaf(w1, v1.x, ax); ay = fmaf(w1, v1.y, ay);
        ax = fmaf(w2, v2.x, ax); ay = fmaf(w2, v2.y, ay);
        ax = fmaf(w3, v3.x, ax); ay = fmaf(w3, v3.y, ay);
    }
    for (; e < end; ++e) {
        float w = ew[e];
        float2 v = bx2f(hprev[(size_t)ecol[e] * 64 + f]);
        ax = fmaf(w, v.x, ax);
        ay = fmaf(w, v.y, ay);
    }
    hnext[(size_t)node * 64 + f] = (unsigned)f2b(ax) | ((unsigned)f2b(ay) << 16);
}

// ---------- MFMA GEMM: out[NP,256] = relu(bias + [s0|s1|s2|s3] @ Wt^T) ----------
// m97 structure: 128x128 tile, 4 waves (2x2 of 64x64), 16x16x32 bf16 MFMA,
// global_load_lds width=16 staging, ds_read_b128 fragments.
#define GLDS(g, l)                                                                      \
    __builtin_amdgcn_global_load_lds((const __attribute__((address_space(1))) void*)(g), \
                                     (__attribute__((address_space(3))) void*)(l), 16, 0, 0)

__global__ __launch_bounds__(256) void gemm_mfma(const short* __restrict__ s0,
                                                 const short* __restrict__ s1,
                                                 const short* __restrict__ s2,
                                                 const short* __restrict__ s3,
                                                 const short* __restrict__ Wt,
                                                 const float* __restrict__ bias,
                                                 float* __restrict__ C) {
    __shared__ short As[128 * 32];   // [m][k] row-major, 8 KB
    __shared__ short Bs[128 * 32];   // [n][k] row-major, 8 KB
    const int t = threadIdx.x;
    const int m0 = blockIdx.x * 128;
    const int n0 = blockIdx.y * 128;
    const int w = t >> 6;
    const int l = t & 63;
    const int wr = (w >> 1) * 64;
    const int wc = (w & 1) * 64;
    const int lm = l & 15;
    const int k8 = (l >> 4) * 8;     // k offset of this lane's fragment

    const short* srcs[4] = {s0, s1, s2, s3};

    floatx4 zero = {0.f, 0.f, 0.f, 0.f};
    floatx4 acc[4][4];
#pragma unroll
    for (int r = 0; r < 4; ++r)
#pragma unroll
        for (int c = 0; c < 4; ++c) acc[r][c] = zero;

    // staging addresses: thread t loads 16 B = row (j*64 + t/4), cols (t&3)*8..+7
    const int sm = t >> 2;           // 0..63
    const int sk = (t & 3) * 8;

    for (int kk = 0; kk < KTOT; kk += 32) {
        const short* Asrc = srcs[kk >> 7] + (kk & 127);
        GLDS(Asrc + (size_t)(m0 + sm) * D + sk, As + w * 512);
        GLDS(Asrc + (size_t)(m0 + 64 + sm) * D + sk, As + 2048 + w * 512);
        const short* Bsrc = Wt + kk;
        GLDS(Bsrc + (size_t)(n0 + sm) * KTOT + sk, Bs + w * 512);
        GLDS(Bsrc + (size_t)(n0 + 64 + sm) * KTOT + sk, Bs + 2048 + w * 512);
        __syncthreads();

        short8 af[4], bfr[4];
#pragma unroll
        for (int r = 0; r < 4; ++r)
            af[r] = *(const short8*)&As[(wr + r * 16 + lm) * 32 + k8];
#pragma unroll
        for (int c = 0; c < 4; ++c)
            bfr[c] = *(const short8*)&Bs[(wc + c * 16 + lm) * 32 + k8];
#pragma unroll
        for (int r = 0; r < 4; ++r)
#pragma unroll
            for (int c = 0; c < 4; ++c)
                acc[r][c] = __builtin_amdgcn_mfma_f32_16x16x32_bf16(af[r], bfr[c], acc[r][c], 0, 0, 0);
        __syncthreads();
    }

    // C/D layout: col = lane&15, row = (lane>>4)*4 + i
    const int q4 = (l >> 4) * 4;
#pragma unroll
    for (int r = 0; r < 4; ++r) {
#pragma unroll
        for (int i = 0; i < 4; ++i) {
            int m = m0 + wr + r * 16 + q4 + i;
            if (m < NN) {
#pragma unroll
                for (int c = 0; c < 4; ++c) {
                    int n = n0 + wc + c * 16 + lm;
                    float v = acc[r][c][i] + bias[n];
                    C[(size_t)m * UNITS + n] = fmaxf(v, 0.f);
                }
            }
        }
    }
}

extern "C" void kernel_launch(void* const* d_in, const int* in_sizes, int n_in,
                              void* d_out, int out_size, void* d_ws, size_t ws_size,
                              hipStream_t stream) {
    const float* x = (const float*)d_in[0];
    const int* ei = (const int*)d_in[1];
    const float* ew_in = (const float*)d_in[2];
    const float* W = (const float*)d_in[3];
    const float* bias = (const float*)d_in[4];
    float* out = (float*)d_out;

    const int* row = ei;
    const int* col = ei + NE;

    // workspace layout (4-byte units)
    float* deg = (float*)d_ws;                  // NN
    float* dis = deg + NN;                      // NN
    int* cnt = (int*)(dis + NN);                // NN
    int* cursor = cnt + NN;                     // NN
    int* row_ptr = cursor + NN;                 // NN+1 (+pad to even)
    int* ecol = row_ptr + NN + 2;               // NE
    float* ewn = (float*)(ecol + NE);           // NE
    unsigned* xb = (unsigned*)(ewn + NE);       // NP*64 uints (bf16x2)
    unsigned* h1b = xb + (size_t)NP * 64;
    unsigned* h2b = h1b + (size_t)NP * 64;
    unsigned* h3b = h2b + (size_t)NP * 64;
    short* Wt = (short*)(h3b + (size_t)NP * 64);  // 256*512 bf16

    hipMemsetAsync(deg, 0, NN * sizeof(float), stream);
    hipMemsetAsync(cnt, 0, NN * sizeof(int), stream);
    hipMemsetAsync(cursor, 0, NN * sizeof(int), stream);

    count_kernel<<<(NE + 255) / 256, 256, 0, stream>>>(row, ew_in, deg, cnt, NE);
    dis_kernel<<<(NN + 255) / 256, 256, 0, stream>>>(deg, dis, NN);
    scan_kernel<<<1, 1024, 0, stream>>>(cnt, row_ptr);
    fill_kernel<<<(NE + 255) / 256, 256, 0, stream>>>(row, col, ew_in, dis, row_ptr, cursor,
                                                      ecol, ewn, NE);

    convx_kernel<<<(NN * D / 4) / 256, 256, 0, stream>>>(x, xb);     // exact grid
    transw_kernel<<<dim3(KTOT / 32, UNITS / 32), 256, 0, stream>>>(W, Wt);

    int gat_blocks = (NN + 3) / 4;
    gather_kernel<<<gat_blocks, 256, 0, stream>>>(xb, h1b, row_ptr, ecol, ewn);
    gather_kernel<<<gat_blocks, 256, 0, stream>>>(h1b, h2b, row_ptr, ecol, ewn);
    gather_kernel<<<gat_blocks, 256, 0, stream>>>(h2b, h3b, row_ptr, ecol, ewn);

    gemm_mfma<<<dim3(NP / 128, UNITS / 128), 256, 0, stream>>>(
        (const short*)xb, (const short*)h1b, (const short*)h2b, (const short*)h3b,
        Wt, bias, out);
}

// Round 5
// 385.874 us; speedup vs baseline: 11.2553x; 1.1916x over previous
//
#include <hip/hip_runtime.h>

#define NN 50000
#define NP 50048   // rows padded to multiple of 128
#define NE 800000
#define D 128
#define UNITS 256
#define KTOT 512
#define SCAN_NB 50   // 50 blocks x 1024 elements covers 50000

typedef __attribute__((ext_vector_type(8))) short short8;
typedef __attribute__((ext_vector_type(4))) float floatx4;

__device__ inline unsigned short f2b(float f) {          // fp32 -> bf16 RNE
    unsigned u = __float_as_uint(f);
    return (unsigned short)((u + 0x7fff + ((u >> 16) & 1)) >> 16);
}
__device__ inline float2 bx2f(unsigned v) {              // packed bf16x2 -> float2
    float2 r;
    r.x = __uint_as_float(v << 16);
    r.y = __uint_as_float(v & 0xffff0000u);
    return r;
}

// ---------- degree + edge counts ----------
__global__ void count_kernel(const int* __restrict__ row, const float* __restrict__ w,
                             float* __restrict__ deg, int* __restrict__ cnt, int E) {
    int e = blockIdx.x * blockDim.x + threadIdx.x;
    if (e < E) {
        int r = row[e];
        atomicAdd(&deg[r], w[e]);
        atomicAdd(&cnt[r], 1);
    }
}

__global__ void dis_kernel(const float* __restrict__ deg, float* __restrict__ dis, int n) {
    int i = blockIdx.x * blockDim.x + threadIdx.x;
    if (i < n) {
        float d = deg[i];
        dis[i] = d > 0.f ? rsqrtf(d) : 0.f;
    }
}

// ---------- 3-phase exclusive scan of cnt -> row_ptr ----------
__global__ __launch_bounds__(256) void scanA_kernel(const int* __restrict__ cnt,
                                                    int* __restrict__ row_ptr,
                                                    int* __restrict__ bsum) {
    __shared__ int s[256];
    int b = blockIdx.x, t = threadIdx.x;
    int base = b * 1024 + t * 4;
    int v[4];
    int sum = 0;
#pragma unroll
    for (int i = 0; i < 4; ++i) {
        int idx = base + i;
        v[i] = (idx < NN) ? cnt[idx] : 0;
        sum += v[i];
    }
    s[t] = sum;
    __syncthreads();
    for (int off = 1; off < 256; off <<= 1) {
        int add = (t >= off) ? s[t - off] : 0;
        __syncthreads();
        s[t] += add;
        __syncthreads();
    }
    int run = s[t] - sum;
#pragma unroll
    for (int i = 0; i < 4; ++i) {
        int idx = base + i;
        if (idx < NN) row_ptr[idx] = run;
        run += v[i];
    }
    if (t == 255) bsum[b] = s[255];
}

__global__ void scanB_kernel(int* __restrict__ bsum, int* __restrict__ row_ptr) {
    if (threadIdx.x == 0 && blockIdx.x == 0) {
        int run = 0;
        for (int i = 0; i < SCAN_NB; ++i) {
            int v = bsum[i];
            bsum[i] = run;
            run += v;
        }
        row_ptr[NN] = run;
    }
}

__global__ __launch_bounds__(256) void scanC_kernel(int* __restrict__ row_ptr,
                                                    const int* __restrict__ bsum) {
    int b = blockIdx.x, t = threadIdx.x;
    int off = bsum[b];
    int base = b * 1024 + t * 4;
#pragma unroll
    for (int i = 0; i < 4; ++i) {
        int idx = base + i;
        if (idx < NN) row_ptr[idx] += off;
    }
}

// ---------- CSR fill: interleaved (col, weight) records ----------
__global__ void fill_kernel(const int* __restrict__ row, const int* __restrict__ col,
                            const float* __restrict__ w, const float* __restrict__ dis,
                            const int* __restrict__ row_ptr, int* __restrict__ cursor,
                            int2* __restrict__ edges, int E) {
    int e = blockIdx.x * blockDim.x + threadIdx.x;
    if (e >= E) return;
    int r = row[e], c = col[e];
    int pos = row_ptr[r] + atomicAdd(&cursor[r], 1);
    float wn = dis[r] * w[e] * dis[c];
    edges[pos] = make_int2(c, __float_as_int(wn));
}

// ---------- fp32 -> bf16 convert (x) ----------
__global__ void convx_kernel(const float* __restrict__ x, unsigned* __restrict__ xb) {
    int t = blockIdx.x * blockDim.x + threadIdx.x;
    float4 v = ((const float4*)x)[t];
    uint2 o;
    o.x = (unsigned)f2b(v.x) | ((unsigned)f2b(v.y) << 16);
    o.y = (unsigned)f2b(v.z) | ((unsigned)f2b(v.w) << 16);
    ((uint2*)xb)[t] = o;
}

// ---------- W[512][256] fp32 -> Wt[256][512] bf16 ----------
__global__ __launch_bounds__(256) void transw_kernel(const float* __restrict__ W,
                                                     short* __restrict__ Wt) {
    __shared__ float tile[32][33];
    int kb = blockIdx.x * 32;
    int nb = blockIdx.y * 32;
    int tx = threadIdx.x & 31, ty = threadIdx.x >> 5;
    for (int i = 0; i < 32; i += 8)
        tile[ty + i][tx] = W[(size_t)(kb + ty + i) * UNITS + nb + tx];
    __syncthreads();
    for (int i = 0; i < 32; i += 8)
        Wt[(size_t)(nb + ty + i) * KTOT + kb + tx] = (short)f2b(tile[tx][ty + i]);
}

// ---------- propagation (bf16 in/out, fp32 accumulate), x8 ILP ----------
__global__ __launch_bounds__(256) void gather_kernel(const unsigned* __restrict__ hprev,
                                                     unsigned* __restrict__ hnext,
                                                     const int* __restrict__ row_ptr,
                                                     const int2* __restrict__ edges) {
    int node = blockIdx.x * 4 + (threadIdx.x >> 6);
    int f = threadIdx.x & 63;
    if (node >= NN) return;
    int beg = row_ptr[node];
    int end = row_ptr[node + 1];
    float2 a = bx2f(hprev[(size_t)node * 64 + f]);  // self loop, weight 1
    float ax = a.x, ay = a.y;
    int e = beg;
    for (; e + 8 <= end; e += 8) {
        int2 E0 = edges[e + 0], E1 = edges[e + 1], E2 = edges[e + 2], E3 = edges[e + 3];
        int2 E4 = edges[e + 4], E5 = edges[e + 5], E6 = edges[e + 6], E7 = edges[e + 7];
        float2 v0 = bx2f(hprev[(size_t)E0.x * 64 + f]);
        float2 v1 = bx2f(hprev[(size_t)E1.x * 64 + f]);
        float2 v2 = bx2f(hprev[(size_t)E2.x * 64 + f]);
        float2 v3 = bx2f(hprev[(size_t)E3.x * 64 + f]);
        float2 v4 = bx2f(hprev[(size_t)E4.x * 64 + f]);
        float2 v5 = bx2f(hprev[(size_t)E5.x * 64 + f]);
        float2 v6 = bx2f(hprev[(size_t)E6.x * 64 + f]);
        float2 v7 = bx2f(hprev[(size_t)E7.x * 64 + f]);
        float w0 = __int_as_float(E0.y), w1 = __int_as_float(E1.y);
        float w2 = __int_as_float(E2.y), w3 = __int_as_float(E3.y);
        float w4 = __int_as_float(E4.y), w5 = __int_as_float(E5.y);
        float w6 = __int_as_float(E6.y), w7 = __int_as_float(E7.y);
        ax = fmaf(w0, v0.x, ax); ay = fmaf(w0, v0.y, ay);
        ax = fmaf(w1, v1.x, ax); ay = fmaf(w1, v1.y, ay);
        ax = fmaf(w2, v2.x, ax); ay = fmaf(w2, v2.y, ay);
        ax = fmaf(w3, v3.x, ax); ay = fmaf(w3, v3.y, ay);
        ax = fmaf(w4, v4.x, ax); ay = fmaf(w4, v4.y, ay);
        ax = fmaf(w5, v5.x, ax); ay = fmaf(w5, v5.y, ay);
        ax = fmaf(w6, v6.x, ax); ay = fmaf(w6, v6.y, ay);
        ax = fmaf(w7, v7.x, ax); ay = fmaf(w7, v7.y, ay);
    }
    for (; e < end; ++e) {
        int2 E = edges[e];
        float w = __int_as_float(E.y);
        float2 v = bx2f(hprev[(size_t)E.x * 64 + f]);
        ax = fmaf(w, v.x, ax);
        ay = fmaf(w, v.y, ay);
    }
    hnext[(size_t)node * 64 + f] = (unsigned)f2b(ax) | ((unsigned)f2b(ay) << 16);
}

// ---------- MFMA GEMM: out[NP,256] = relu(bias + [s0|s1|s2|s3] @ Wt^T) ----------
#define GLDS(g, l)                                                                      \
    __builtin_amdgcn_global_load_lds((const __attribute__((address_space(1))) void*)(g), \
                                     (__attribute__((address_space(3))) void*)(l), 16, 0, 0)

__global__ __launch_bounds__(256) void gemm_mfma(const short* __restrict__ s0,
                                                 const short* __restrict__ s1,
                                                 const short* __restrict__ s2,
                                                 const short* __restrict__ s3,
                                                 const short* __restrict__ Wt,
                                                 const float* __restrict__ bias,
                                                 float* __restrict__ C) {
    __shared__ short As[128 * 32];
    __shared__ short Bs[128 * 32];
    const int t = threadIdx.x;
    const int m0 = blockIdx.x * 128;
    const int n0 = blockIdx.y * 128;
    const int w = t >> 6;
    const int l = t & 63;
    const int wr = (w >> 1) * 64;
    const int wc = (w & 1) * 64;
    const int lm = l & 15;
    const int k8 = (l >> 4) * 8;

    const short* srcs[4] = {s0, s1, s2, s3};

    floatx4 zero = {0.f, 0.f, 0.f, 0.f};
    floatx4 acc[4][4];
#pragma unroll
    for (int r = 0; r < 4; ++r)
#pragma unroll
        for (int c = 0; c < 4; ++c) acc[r][c] = zero;

    const int sm = t >> 2;
    const int sk = (t & 3) * 8;

    for (int kk = 0; kk < KTOT; kk += 32) {
        const short* Asrc = srcs[kk >> 7] + (kk & 127);
        GLDS(Asrc + (size_t)(m0 + sm) * D + sk, As + w * 512);
        GLDS(Asrc + (size_t)(m0 + 64 + sm) * D + sk, As + 2048 + w * 512);
        const short* Bsrc = Wt + kk;
        GLDS(Bsrc + (size_t)(n0 + sm) * KTOT + sk, Bs + w * 512);
        GLDS(Bsrc + (size_t)(n0 + 64 + sm) * KTOT + sk, Bs + 2048 + w * 512);
        __syncthreads();

        short8 af[4], bfr[4];
#pragma unroll
        for (int r = 0; r < 4; ++r)
            af[r] = *(const short8*)&As[(wr + r * 16 + lm) * 32 + k8];
#pragma unroll
        for (int c = 0; c < 4; ++c)
            bfr[c] = *(const short8*)&Bs[(wc + c * 16 + lm) * 32 + k8];
#pragma unroll
        for (int r = 0; r < 4; ++r)
#pragma unroll
            for (int c = 0; c < 4; ++c)
                acc[r][c] = __builtin_amdgcn_mfma_f32_16x16x32_bf16(af[r], bfr[c], acc[r][c], 0, 0, 0);
        __syncthreads();
    }

    const int q4 = (l >> 4) * 4;
#pragma unroll
    for (int r = 0; r < 4; ++r) {
#pragma unroll
        for (int i = 0; i < 4; ++i) {
            int m = m0 + wr + r * 16 + q4 + i;
            if (m < NN) {
#pragma unroll
                for (int c = 0; c < 4; ++c) {
                    int n = n0 + wc + c * 16 + lm;
                    float v = acc[r][c][i] + bias[n];
                    C[(size_t)m * UNITS + n] = fmaxf(v, 0.f);
                }
            }
        }
    }
}

extern "C" void kernel_launch(void* const* d_in, const int* in_sizes, int n_in,
                              void* d_out, int out_size, void* d_ws, size_t ws_size,
                              hipStream_t stream) {
    const float* x = (const float*)d_in[0];
    const int* ei = (const int*)d_in[1];
    const float* ew_in = (const float*)d_in[2];
    const float* W = (const float*)d_in[3];
    const float* bias = (const float*)d_in[4];
    float* out = (float*)d_out;

    const int* row = ei;
    const int* col = ei + NE;

    // workspace layout (4-byte units)
    float* deg = (float*)d_ws;                  // NN
    float* dis = deg + NN;                      // NN
    int* cnt = (int*)(dis + NN);                // NN
    int* cursor = cnt + NN;                     // NN
    int* bsum = cursor + NN;                    // SCAN_NB (+pad)
    int* row_ptr = bsum + 64;                   // NN+1 (+pad to even)
    int2* edges = (int2*)(row_ptr + NN + 2);    // NE int2
    unsigned* xb = (unsigned*)(edges + NE);     // NP*64 uints (bf16x2)
    unsigned* h1b = xb + (size_t)NP * 64;
    unsigned* h2b = h1b + (size_t)NP * 64;
    unsigned* h3b = h2b + (size_t)NP * 64;
    short* Wt = (short*)(h3b + (size_t)NP * 64);  // 256*512 bf16

    hipMemsetAsync(deg, 0, NN * sizeof(float), stream);
    hipMemsetAsync(cnt, 0, NN * sizeof(int), stream);
    hipMemsetAsync(cursor, 0, NN * sizeof(int), stream);

    count_kernel<<<(NE + 255) / 256, 256, 0, stream>>>(row, ew_in, deg, cnt, NE);
    dis_kernel<<<(NN + 255) / 256, 256, 0, stream>>>(deg, dis, NN);
    scanA_kernel<<<SCAN_NB, 256, 0, stream>>>(cnt, row_ptr, bsum);
    scanB_kernel<<<1, 64, 0, stream>>>(bsum, row_ptr);
    scanC_kernel<<<SCAN_NB, 256, 0, stream>>>(row_ptr, bsum);
    fill_kernel<<<(NE + 255) / 256, 256, 0, stream>>>(row, col, ew_in, dis, row_ptr, cursor,
                                                      edges, NE);

    convx_kernel<<<(NN * D / 4) / 256, 256, 0, stream>>>(x, xb);
    transw_kernel<<<dim3(KTOT / 32, UNITS / 32), 256, 0, stream>>>(W, Wt);

    int gat_blocks = (NN + 3) / 4;
    gather_kernel<<<gat_blocks, 256, 0, stream>>>(xb, h1b, row_ptr, edges);
    gather_kernel<<<gat_blocks, 256, 0, stream>>>(h1b, h2b, row_ptr, edges);
    gather_kernel<<<gat_blocks, 256, 0, stream>>>(h2b, h3b, row_ptr, edges);

    gemm_mfma<<<dim3(NP / 128, UNITS / 128), 256, 0, stream>>>(
        (const short*)xb, (const short*)h1b, (const short*)h2b, (const short*)h3b,
        Wt, bias, out);
}

// Round 6
// 345.361 us; speedup vs baseline: 12.5757x; 1.1173x over previous
//
#include <hip/hip_runtime.h>

#define NN 50000
#define NP 50048   // rows padded to multiple of 128
#define NE 800000
#define D 128
#define UNITS 256
#define KTOT 512
#define SCAN_NB 50   // 50 blocks x 1024 elements covers 50000

typedef __attribute__((ext_vector_type(8))) short short8;
typedef __attribute__((ext_vector_type(4))) float floatx4;

__device__ inline unsigned short f2b(float f) {          // fp32 -> bf16 RNE
    unsigned u = __float_as_uint(f);
    return (unsigned short)((u + 0x7fff + ((u >> 16) & 1)) >> 16);
}
__device__ inline float2 bx2f(unsigned v) {              // packed bf16x2 -> float2
    float2 r;
    r.x = __uint_as_float(v << 16);
    r.y = __uint_as_float(v & 0xffff0000u);
    return r;
}

// ---------- count: replicated histograms (contention /4) + per-edge rank ----------
__global__ void count_kernel(const int* __restrict__ row, int* __restrict__ cnt4,
                             int* __restrict__ rank, int E) {
    int e = blockIdx.x * blockDim.x + threadIdx.x;
    if (e < E) {
        int rep = (e >> 6) & 3;                 // whole wave -> same replica
        rank[e] = atomicAdd(&cnt4[rep * NN + row[e]], 1);
    }
}

// ---------- 3-phase exclusive scan; also prefixes the 4 replicas per node ----------
__global__ __launch_bounds__(256) void scanA_kernel(int* __restrict__ cnt4,
                                                    int* __restrict__ row_ptr,
                                                    int* __restrict__ bsum) {
    __shared__ int s[256];
    int b = blockIdx.x, t = threadIdx.x;
    int base = b * 1024 + t * 4;
    int v[4];
    int sum = 0;
#pragma unroll
    for (int i = 0; i < 4; ++i) {
        int idx = base + i;
        int tot = 0;
        if (idx < NN) {
            int c0 = cnt4[idx];
            int c1 = cnt4[NN + idx];
            int c2 = cnt4[2 * NN + idx];
            int c3 = cnt4[3 * NN + idx];
            cnt4[idx] = 0;
            cnt4[NN + idx] = c0;
            cnt4[2 * NN + idx] = c0 + c1;
            cnt4[3 * NN + idx] = c0 + c1 + c2;
            tot = c0 + c1 + c2 + c3;
        }
        v[i] = tot;
        sum += tot;
    }
    s[t] = sum;
    __syncthreads();
    for (int off = 1; off < 256; off <<= 1) {
        int add = (t >= off) ? s[t - off] : 0;
        __syncthreads();
        s[t] += add;
        __syncthreads();
    }
    int run = s[t] - sum;
#pragma unroll
    for (int i = 0; i < 4; ++i) {
        int idx = base + i;
        if (idx < NN) row_ptr[idx] = run;
        run += v[i];
    }
    if (t == 255) bsum[b] = s[255];
}

__global__ void scanB_kernel(int* __restrict__ bsum, int* __restrict__ row_ptr) {
    if (threadIdx.x == 0 && blockIdx.x == 0) {
        int run = 0;
        for (int i = 0; i < SCAN_NB; ++i) {
            int v = bsum[i];
            bsum[i] = run;
            run += v;
        }
        row_ptr[NN] = run;
    }
}

__global__ __launch_bounds__(256) void scanC_kernel(int* __restrict__ row_ptr,
                                                    const int* __restrict__ bsum) {
    int b = blockIdx.x, t = threadIdx.x;
    int off = bsum[b];
    int base = b * 1024 + t * 4;
#pragma unroll
    for (int i = 0; i < 4; ++i) {
        int idx = base + i;
        if (idx < NN) row_ptr[idx] += off;
    }
}

// ---------- CSR fill (no atomics): (col, raw weight) records ----------
__global__ void fill_kernel(const int* __restrict__ row, const int* __restrict__ col,
                            const float* __restrict__ w, const int* __restrict__ rank,
                            const int* __restrict__ row_ptr, const int* __restrict__ cnt4,
                            int2* __restrict__ edges, int E) {
    int e = blockIdx.x * blockDim.x + threadIdx.x;
    if (e >= E) return;
    int r = row[e];
    int rep = (e >> 6) & 3;
    int pos = row_ptr[r] + cnt4[rep * NN + r] + rank[e];
    edges[pos] = make_int2(col[e], __float_as_int(w[e]));
}

// ---------- per-node degree -> dis (no atomics) ----------
__global__ void degdis_kernel(const int* __restrict__ row_ptr, const int2* __restrict__ edges,
                              float* __restrict__ dis) {
    int n = blockIdx.x * blockDim.x + threadIdx.x;
    if (n >= NN) return;
    int beg = row_ptr[n], end = row_ptr[n + 1];
    float s = 0.f;
    for (int e = beg; e < end; ++e) s += __int_as_float(edges[e].y);
    dis[n] = s > 0.f ? rsqrtf(s) : 0.f;
}

// ---------- per-node weight normalization in place ----------
__global__ void norm_kernel(const int* __restrict__ row_ptr, const float* __restrict__ dis,
                            int2* __restrict__ edges) {
    int n = blockIdx.x * blockDim.x + threadIdx.x;
    if (n >= NN) return;
    int beg = row_ptr[n], end = row_ptr[n + 1];
    float dr = dis[n];
    for (int e = beg; e < end; ++e) {
        int2 E = edges[e];
        float wn = dr * __int_as_float(E.y) * dis[E.x];
        edges[e].y = __float_as_int(wn);
    }
}

// ---------- fp32 -> bf16 convert (x) ----------
__global__ void convx_kernel(const float* __restrict__ x, unsigned* __restrict__ xb) {
    int t = blockIdx.x * blockDim.x + threadIdx.x;
    float4 v = ((const float4*)x)[t];
    uint2 o;
    o.x = (unsigned)f2b(v.x) | ((unsigned)f2b(v.y) << 16);
    o.y = (unsigned)f2b(v.z) | ((unsigned)f2b(v.w) << 16);
    ((uint2*)xb)[t] = o;
}

// ---------- W[512][256] fp32 -> Wt[256][512] bf16 ----------
__global__ __launch_bounds__(256) void transw_kernel(const float* __restrict__ W,
                                                     short* __restrict__ Wt) {
    __shared__ float tile[32][33];
    int kb = blockIdx.x * 32;
    int nb = blockIdx.y * 32;
    int tx = threadIdx.x & 31, ty = threadIdx.x >> 5;
    for (int i = 0; i < 32; i += 8)
        tile[ty + i][tx] = W[(size_t)(kb + ty + i) * UNITS + nb + tx];
    __syncthreads();
    for (int i = 0; i < 32; i += 8)
        Wt[(size_t)(nb + ty + i) * KTOT + kb + tx] = (short)f2b(tile[tx][ty + i]);
}

// ---------- propagation (bf16 in/out, fp32 accumulate), x8 ILP ----------
__global__ __launch_bounds__(256) void gather_kernel(const unsigned* __restrict__ hprev,
                                                     unsigned* __restrict__ hnext,
                                                     const int* __restrict__ row_ptr,
                                                     const int2* __restrict__ edges) {
    int node = blockIdx.x * 4 + (threadIdx.x >> 6);
    int f = threadIdx.x & 63;
    if (node >= NN) return;
    int beg = row_ptr[node];
    int end = row_ptr[node + 1];
    float2 a = bx2f(hprev[(size_t)node * 64 + f]);  // self loop, weight 1
    float ax = a.x, ay = a.y;
    int e = beg;
    for (; e + 8 <= end; e += 8) {
        int2 E0 = edges[e + 0], E1 = edges[e + 1], E2 = edges[e + 2], E3 = edges[e + 3];
        int2 E4 = edges[e + 4], E5 = edges[e + 5], E6 = edges[e + 6], E7 = edges[e + 7];
        float2 v0 = bx2f(hprev[(size_t)E0.x * 64 + f]);
        float2 v1 = bx2f(hprev[(size_t)E1.x * 64 + f]);
        float2 v2 = bx2f(hprev[(size_t)E2.x * 64 + f]);
        float2 v3 = bx2f(hprev[(size_t)E3.x * 64 + f]);
        float2 v4 = bx2f(hprev[(size_t)E4.x * 64 + f]);
        float2 v5 = bx2f(hprev[(size_t)E5.x * 64 + f]);
        float2 v6 = bx2f(hprev[(size_t)E6.x * 64 + f]);
        float2 v7 = bx2f(hprev[(size_t)E7.x * 64 + f]);
        float w0 = __int_as_float(E0.y), w1 = __int_as_float(E1.y);
        float w2 = __int_as_float(E2.y), w3 = __int_as_float(E3.y);
        float w4 = __int_as_float(E4.y), w5 = __int_as_float(E5.y);
        float w6 = __int_as_float(E6.y), w7 = __int_as_float(E7.y);
        ax = fmaf(w0, v0.x, ax); ay = fmaf(w0, v0.y, ay);
        ax = fmaf(w1, v1.x, ax); ay = fmaf(w1, v1.y, ay);
        ax = fmaf(w2, v2.x, ax); ay = fmaf(w2, v2.y, ay);
        ax = fmaf(w3, v3.x, ax); ay = fmaf(w3, v3.y, ay);
        ax = fmaf(w4, v4.x, ax); ay = fmaf(w4, v4.y, ay);
        ax = fmaf(w5, v5.x, ax); ay = fmaf(w5, v5.y, ay);
        ax = fmaf(w6, v6.x, ax); ay = fmaf(w6, v6.y, ay);
        ax = fmaf(w7, v7.x, ax); ay = fmaf(w7, v7.y, ay);
    }
    for (; e < end; ++e) {
        int2 E = edges[e];
        float w = __int_as_float(E.y);
        float2 v = bx2f(hprev[(size_t)E.x * 64 + f]);
        ax = fmaf(w, v.x, ax);
        ay = fmaf(w, v.y, ay);
    }
    hnext[(size_t)node * 64 + f] = (unsigned)f2b(ax) | ((unsigned)f2b(ay) << 16);
}

// ---------- MFMA GEMM: out[NP,256] = relu(bias + [s0|s1|s2|s3] @ Wt^T) ----------
#define GLDS(g, l)                                                                      \
    __builtin_amdgcn_global_load_lds((const __attribute__((address_space(1))) void*)(g), \
                                     (__attribute__((address_space(3))) void*)(l), 16, 0, 0)

__global__ __launch_bounds__(256) void gemm_mfma(const short* __restrict__ s0,
                                                 const short* __restrict__ s1,
                                                 const short* __restrict__ s2,
                                                 const short* __restrict__ s3,
                                                 const short* __restrict__ Wt,
                                                 const float* __restrict__ bias,
                                                 float* __restrict__ C) {
    __shared__ short As[128 * 32];
    __shared__ short Bs[128 * 32];
    const int t = threadIdx.x;
    const int m0 = blockIdx.x * 128;
    const int n0 = blockIdx.y * 128;
    const int w = t >> 6;
    const int l = t & 63;
    const int wr = (w >> 1) * 64;
    const int wc = (w & 1) * 64;
    const int lm = l & 15;
    const int k8 = (l >> 4) * 8;

    const short* srcs[4] = {s0, s1, s2, s3};

    floatx4 zero = {0.f, 0.f, 0.f, 0.f};
    floatx4 acc[4][4];
#pragma unroll
    for (int r = 0; r < 4; ++r)
#pragma unroll
        for (int c = 0; c < 4; ++c) acc[r][c] = zero;

    const int sm = t >> 2;
    const int sk = (t & 3) * 8;

    for (int kk = 0; kk < KTOT; kk += 32) {
        const short* Asrc = srcs[kk >> 7] + (kk & 127);
        GLDS(Asrc + (size_t)(m0 + sm) * D + sk, As + w * 512);
        GLDS(Asrc + (size_t)(m0 + 64 + sm) * D + sk, As + 2048 + w * 512);
        const short* Bsrc = Wt + kk;
        GLDS(Bsrc + (size_t)(n0 + sm) * KTOT + sk, Bs + w * 512);
        GLDS(Bsrc + (size_t)(n0 + 64 + sm) * KTOT + sk, Bs + 2048 + w * 512);
        __syncthreads();

        short8 af[4], bfr[4];
#pragma unroll
        for (int r = 0; r < 4; ++r)
            af[r] = *(const short8*)&As[(wr + r * 16 + lm) * 32 + k8];
#pragma unroll
        for (int c = 0; c < 4; ++c)
            bfr[c] = *(const short8*)&Bs[(wc + c * 16 + lm) * 32 + k8];
#pragma unroll
        for (int r = 0; r < 4; ++r)
#pragma unroll
            for (int c = 0; c < 4; ++c)
                acc[r][c] = __builtin_amdgcn_mfma_f32_16x16x32_bf16(af[r], bfr[c], acc[r][c], 0, 0, 0);
        __syncthreads();
    }

    const int q4 = (l >> 4) * 4;
#pragma unroll
    for (int r = 0; r < 4; ++r) {
#pragma unroll
        for (int i = 0; i < 4; ++i) {
            int m = m0 + wr + r * 16 + q4 + i;
            if (m < NN) {
#pragma unroll
                for (int c = 0; c < 4; ++c) {
                    int n = n0 + wc + c * 16 + lm;
                    float v = acc[r][c][i] + bias[n];
                    C[(size_t)m * UNITS + n] = fmaxf(v, 0.f);
                }
            }
        }
    }
}

extern "C" void kernel_launch(void* const* d_in, const int* in_sizes, int n_in,
                              void* d_out, int out_size, void* d_ws, size_t ws_size,
                              hipStream_t stream) {
    const float* x = (const float*)d_in[0];
    const int* ei = (const int*)d_in[1];
    const float* ew_in = (const float*)d_in[2];
    const float* W = (const float*)d_in[3];
    const float* bias = (const float*)d_in[4];
    float* out = (float*)d_out;

    const int* row = ei;
    const int* col = ei + NE;

    // workspace layout (4-byte units)
    float* dis = (float*)d_ws;                  // NN
    int* cnt4 = (int*)(dis + NN);               // 4*NN
    int* rank = cnt4 + 4 * NN;                  // NE
    int* bsum = rank + NE;                      // 64
    int* row_ptr = bsum + 64;                   // NN+2 (even pad; running total even)
    int2* edges = (int2*)(row_ptr + NN + 2);    // NE int2 (8B aligned)
    unsigned* xb = (unsigned*)(edges + NE);     // NP*64 uints (bf16x2)
    unsigned* h1b = xb + (size_t)NP * 64;
    unsigned* h2b = h1b + (size_t)NP * 64;
    unsigned* h3b = h2b + (size_t)NP * 64;
    short* Wt = (short*)(h3b + (size_t)NP * 64);  // 256*512 bf16

    hipMemsetAsync(cnt4, 0, 4 * NN * sizeof(int), stream);

    count_kernel<<<(NE + 255) / 256, 256, 0, stream>>>(row, cnt4, rank, NE);
    scanA_kernel<<<SCAN_NB, 256, 0, stream>>>(cnt4, row_ptr, bsum);
    scanB_kernel<<<1, 64, 0, stream>>>(bsum, row_ptr);
    scanC_kernel<<<SCAN_NB, 256, 0, stream>>>(row_ptr, bsum);
    fill_kernel<<<(NE + 255) / 256, 256, 0, stream>>>(row, col, ew_in, rank, row_ptr, cnt4,
                                                      edges, NE);
    degdis_kernel<<<(NN + 255) / 256, 256, 0, stream>>>(row_ptr, edges, dis);
    norm_kernel<<<(NN + 255) / 256, 256, 0, stream>>>(row_ptr, dis, edges);

    convx_kernel<<<(NN * D / 4) / 256, 256, 0, stream>>>(x, xb);
    transw_kernel<<<dim3(KTOT / 32, UNITS / 32), 256, 0, stream>>>(W, Wt);

    int gat_blocks = (NN + 3) / 4;
    gather_kernel<<<gat_blocks, 256, 0, stream>>>(xb, h1b, row_ptr, edges);
    gather_kernel<<<gat_blocks, 256, 0, stream>>>(h1b, h2b, row_ptr, edges);
    gather_kernel<<<gat_blocks, 256, 0, stream>>>(h2b, h3b, row_ptr, edges);

    gemm_mfma<<<dim3(NP / 128, UNITS / 128), 256, 0, stream>>>(
        (const short*)xb, (const short*)h1b, (const short*)h2b, (const short*)h3b,
        Wt, bias, out);
}